// Round 19
// baseline (202.050 us; speedup 1.0000x reference)
//
#include <hip/hip_runtime.h>

#define DD 512
#define SCAN_B 256
#define BM 128
#define BN 128
#define BK 32
#define NSTEP 16
typedef unsigned short u16;
typedef unsigned int u32;
typedef unsigned char u8;

typedef __attribute__((ext_vector_type(8))) __bf16 bf16v8;
typedef __attribute__((ext_vector_type(2))) __bf16 bf16v2;
typedef __attribute__((ext_vector_type(4))) float f32x4;

// native RNE f32->bf16 (v_cvt_pk_bf16_f32 for pairs)
__device__ __forceinline__ u32 pk2(float a, float b) {
  bf16v2 v;
  v[0] = (__bf16)a;
  v[1] = (__bf16)b;
  return __builtin_bit_cast(u32, v);
}
__device__ __forceinline__ u16 f2bf(float f) {
  return __builtin_bit_cast(u16, (__bf16)f);
}
__device__ __forceinline__ float bf2f(u32 h) {
  return __builtin_bit_cast(float, h << 16);
}

// counted-vmcnt barrier: keep the N newest VMEM ops in flight across it
#define BAR_N(N)                                                        \
  do {                                                                  \
    __builtin_amdgcn_sched_barrier(0);                                  \
    asm volatile("s_waitcnt vmcnt(" #N ") lgkmcnt(0)\n\ts_barrier" ::: "memory"); \
  } while (0)

// ---------------- W[k][n] f32 -> Wt[n][k] bf16 (LDS-tiled transpose) ----------------
__global__ __launch_bounds__(256) void wconv_t(const float* __restrict__ W,
                                               u16* __restrict__ Wt) {
  __shared__ float sm[64][65];
  const int bx = blockIdx.x;   // k tile
  const int by = blockIdx.y;   // n tile
  const int t = threadIdx.x;
  const int r = t >> 6;
  const int c = t & 63;
#pragma unroll
  for (int i = 0; i < 64; i += 4)
    sm[i + r][c] = W[(size_t)(bx * 64 + i + r) * DD + by * 64 + c];
  __syncthreads();
#pragma unroll
  for (int i = 0; i < 64; i += 4) {
    const int n = by * 64 + i + r;
    const int k = bx * 64 + c;
    Wt[(size_t)n * DD + k] = f2bf(sm[c][i + r]);
  }
}

// ---- B-direct pipelined fused GEMM: X[Mpad,512](bf16) = bf16(mask(A f32)) @ Wt^T ----
// BM=128 x BN=128 x BK=32, 512 threads (8 waves, 2x4, 64x32 tile/wave), 16 steps.
// KEY CHANGE (r19): B fragments load DIRECTLY from L2-resident Wt (512 KB) into
// registers -- no B staging, no B in the barrier path. Barrier fences only the
// 8 KB A-tile. LDS 16 KB + ~105 VGPR -> 4 blocks/CU (2x TLP vs r16).
// A: verified r13 staging (f32 load -> mask -> cvt_pk -> ds_write, XOR swizzle),
// 3-parity reg prefetch (A(t+2) issued at step t -> ~1.8 steps flight).
// BAR_N(2) keeps A(t+2)x2 in flight across the barrier.
__global__ __launch_bounds__(512, 4) void gemm_pipe(const float* __restrict__ A,
                                                    const u16* __restrict__ Bt,
                                                    u16* __restrict__ X,
                                                    const u8* __restrict__ flg, int M) {
  __shared__ __align__(16) u16 ldsA[2][BM * BK];   // 2 x 8 KB
  const int tid = threadIdx.x;
  const int lane = tid & 63;
  const int w = tid >> 6;        // 0..7
  const int wm = w >> 2;         // 0..1  (64 rows)
  const int wn = w & 3;          // 0..3  (32 cols)

  // bijective XCD swizzle (ERRATA #11): units 4s..4s+3 = stripe s's col tiles
  const int nwg = gridDim.x;
  const int b = blockIdx.x;
  const int xcd = b & 7, jj = b >> 3;
  const int q = nwg >> 3, r_ = nwg & 7;
  const int unit = (xcd < r_ ? xcd * (q + 1) : r_ * (q + 1) + (xcd - r_) * q) + jj;
  const int row0 = (unit >> 2) * BM;
  const int colB = (unit & 3) * BN;

  const int lr = lane & 15;
  const int kg = lane >> 4;

  f32x4 acc[4][2] = {};

  // A staging (r13 verified): thread t stages chunk t (row=t>>2, slot kc=t&3,
  // global chunk gk = kc ^ ((row>>1)&3))
  const int arow = tid >> 2;
  const int agk = (tid & 3) ^ ((arow >> 1) & 3);
  int ar = row0 + arow;
  if (ar >= M) ar = M - 1;            // pad rows: garbage x, never read
  const float* gA = A + (size_t)ar * DD + agk * 8;
  const int laoff = tid * 8;
  const u32 akeep = flg[ar] ? 0u : 0xFFFFFFFFu;   // masked row -> zero pack

  // B-direct: per-lane fragment pointers into L2-resident Wt
  const u16* gB0 = Bt + (size_t)(colB + wn * 32 + lr) * DD + kg * 8;
  const u16* gB1 = Bt + (size_t)(colB + wn * 32 + 16 + lr) * DD + kg * 8;

  f32x4 rP[3][2];   // A reg prefetch, 3 parities (static idx after full unroll)

  // ---- prologue: load A(0),A(1); stage A(0); barrier ----
  rP[0][0] = *(const f32x4*)(gA);
  rP[0][1] = *(const f32x4*)(gA + 4);
  rP[1][0] = *(const f32x4*)(gA + BK);
  rP[1][1] = *(const f32x4*)(gA + BK + 4);
  {
    uint4 pk;
    pk.x = pk2(rP[0][0].x, rP[0][0].y) & akeep;
    pk.y = pk2(rP[0][0].z, rP[0][0].w) & akeep;
    pk.z = pk2(rP[0][1].x, rP[0][1].y) & akeep;
    pk.w = pk2(rP[0][1].z, rP[0][1].w) & akeep;
    *(uint4*)&ldsA[0][laoff] = pk;   // implicit vmcnt retires A(0), keeps A(1)
  }
  BAR_N(2);   // A(1)x2 stays in flight

#pragma unroll
  for (int t = 0; t < NSTEP; ++t) {
    // B(t) fragments: direct L2 loads (issued first -> MFMA wait retires only
    // these, keeping the A(t+2) prefetch below in flight)
    bf16v8 bfr[2];
    bfr[0] = *(const bf16v8*)(gB0 + t * BK);
    bfr[1] = *(const bf16v8*)(gB1 + t * BK);

    // A(t+2) prefetch into freed parity
    if (t + 2 < NSTEP) {
      rP[(t + 2) % 3][0] = *(const f32x4*)(gA + (t + 2) * BK);
      rP[(t + 2) % 3][1] = *(const f32x4*)(gA + (t + 2) * BK + 4);
    }

    // A fragments from current LDS buffer
    bf16v8 af[4];
#pragma unroll
    for (int m = 0; m < 4; ++m) {
      const int row = wm * 64 + m * 16 + lr;
      const int kc = kg ^ ((row >> 1) & 3);
      af[m] = *(const bf16v8*)&ldsA[t & 1][row * BK + kc * 8];
    }
#pragma unroll
    for (int m = 0; m < 4; ++m)
#pragma unroll
      for (int n = 0; n < 2; ++n)
        acc[m][n] = __builtin_amdgcn_mfma_f32_16x16x32_bf16(af[m], bfr[n], acc[m][n], 0, 0, 0);

    // stage A(t+1) into ldsA[(t+1)&1]; implicit vmcnt retires A(t+1) loads
    // (issued at step t-1 -> ~1.8 steps of flight)
    if (t + 1 < NSTEP) {
      const f32x4 p0 = rP[(t + 1) % 3][0];
      const f32x4 p1 = rP[(t + 1) % 3][1];
      uint4 pk;
      pk.x = pk2(p0.x, p0.y) & akeep;
      pk.y = pk2(p0.z, p0.w) & akeep;
      pk.z = pk2(p1.x, p1.y) & akeep;
      pk.w = pk2(p1.z, p1.w) & akeep;
      *(uint4*)&ldsA[(t + 1) & 1][laoff] = pk;
    }

    // barrier fences ONLY the A-tile; keep A(t+2)x2 in flight
    if (t < NSTEP - 2)      BAR_N(2);
    else if (t < NSTEP - 1) BAR_N(0);
    // t == NSTEP-1: no barrier (epilogue uses regs only)
  }

  // C/D layout: col = lane&15, row = (lane>>4)*4 + reg
  const int crow = (lane >> 4) * 4;
  const int ccol = lane & 15;
#pragma unroll
  for (int m = 0; m < 4; ++m) {
    const int rowb = row0 + wm * 64 + m * 16 + crow;
#pragma unroll
    for (int n = 0; n < 2; ++n) {
      const int col = colB + wn * 32 + n * 16 + ccol;
#pragma unroll
      for (int r = 0; r < 4; ++r)
        X[(size_t)(rowb + r) * DD + col] = f2bf(acc[m][n][r]);
    }
  }
}

// ---- hist + flag_build fused (grid covers n_edges >= n_mask) ----
__global__ __launch_bounds__(256) void hist_flag(const int* __restrict__ dst,
                                                 int* __restrict__ counts,
                                                 const int* __restrict__ mask,
                                                 u8* __restrict__ flg,
                                                 float* __restrict__ out_tail,
                                                 int n, int nm) {
  const int i = blockIdx.x * blockDim.x + threadIdx.x;
  if (i < n) atomicAdd(&counts[dst[i]], 1);
  if (i < nm) {
    const int r = mask[i];
    flg[r] = 1;
    out_tail[i] = (float)r;
  }
}

__global__ __launch_bounds__(SCAN_B) void scanA(const int* __restrict__ counts,
                                                int* __restrict__ lscan,
                                                int* __restrict__ blockSums, int n) {
  __shared__ int sm[SCAN_B];
  const int t = threadIdx.x;
  const int i = blockIdx.x * SCAN_B + t;
  const int v = (i < n) ? counts[i] : 0;
  sm[t] = v;
  __syncthreads();
  for (int off = 1; off < SCAN_B; off <<= 1) {
    int add = (t >= off) ? sm[t - off] : 0;
    __syncthreads();
    sm[t] += add;
    __syncthreads();
  }
  if (i < n) lscan[i] = sm[t] - v;
  if (t == SCAN_B - 1) blockSums[blockIdx.x] = sm[t];
}

// scanC: each block re-scans the (<=256) block sums locally for its base,
// then finalizes offsets + cursor (scanB folded in).
__global__ __launch_bounds__(SCAN_B) void scanC(int* __restrict__ lscan,
                                                const int* __restrict__ blockSums,
                                                int* __restrict__ cursor, int n, int nb) {
  __shared__ int sm[SCAN_B];
  const int t = threadIdx.x;
  const int v = (t < nb) ? blockSums[t] : 0;
  sm[t] = v;
  __syncthreads();
  for (int off = 1; off < SCAN_B; off <<= 1) {
    int add = (t >= off) ? sm[t - off] : 0;
    __syncthreads();
    sm[t] += add;
    __syncthreads();
  }
  const int base = sm[blockIdx.x] - ((blockIdx.x < nb) ? blockSums[blockIdx.x] : 0);
  const int i = blockIdx.x * SCAN_B + t;
  if (i < n) {
    const int o = lscan[i] + base;
    lscan[i] = o;
    cursor[i] = o;
  }
}

// scatter into dst-sorted order; edge payload packed as (src, val) int2
__global__ __launch_bounds__(256) void scatter_sort(const int* __restrict__ src,
                                                    const int* __restrict__ dst,
                                                    const float* __restrict__ ev,
                                                    int* __restrict__ cursor,
                                                    int2* __restrict__ esp, int n) {
  const int i = blockIdx.x * blockDim.x + threadIdx.x;
  if (i < n) {
    const int pos = atomicAdd(&cursor[dst[i]], 1);
    esp[pos] = make_int2(src[i], __float_as_int(ev[i]));
  }
}

// ------------- per-node accumulation from bf16 x, f32 accumulate -------------
// one wave per node; 8x-unrolled edge loop (fabric-BW-bound per r15/r16 tests)
__global__ __launch_bounds__(256) void aggregate(const u16* __restrict__ x,
                                                 const int2* __restrict__ esp,
                                                 const int* __restrict__ offsets,
                                                 const int* __restrict__ counts,
                                                 float* __restrict__ out, int n_nodes) {
  const int node = blockIdx.x * 4 + (threadIdx.x >> 6);
  if (node >= n_nodes) return;
  const int lane = threadIdx.x & 63;
  const int b = offsets[node];
  const int e = b + counts[node];
  float acc[8] = {};
  int j = b;
#define AGG1(U, V)                                      \
  do {                                                  \
    acc[0] = fmaf(V, bf2f(U.x & 0xffffu), acc[0]);      \
    acc[1] = fmaf(V, bf2f(U.x >> 16),     acc[1]);      \
    acc[2] = fmaf(V, bf2f(U.y & 0xffffu), acc[2]);      \
    acc[3] = fmaf(V, bf2f(U.y >> 16),     acc[3]);      \
    acc[4] = fmaf(V, bf2f(U.z & 0xffffu), acc[4]);      \
    acc[5] = fmaf(V, bf2f(U.z >> 16),     acc[5]);      \
    acc[6] = fmaf(V, bf2f(U.w & 0xffffu), acc[6]);      \
    acc[7] = fmaf(V, bf2f(U.w >> 16),     acc[7]);      \
  } while (0)
  for (; j + 8 <= e; j += 8) {
    int2 p[8];
    uint4 u[8];
#pragma unroll
    for (int k = 0; k < 8; ++k) p[k] = esp[j + k];
#pragma unroll
    for (int k = 0; k < 8; ++k)
      u[k] = *(const uint4*)(x + (size_t)p[k].x * DD + lane * 8);
#pragma unroll
    for (int k = 0; k < 8; ++k) AGG1(u[k], __int_as_float(p[k].y));
  }
  for (; j + 4 <= e; j += 4) {
    const int2 p0 = esp[j], p1 = esp[j + 1], p2 = esp[j + 2], p3 = esp[j + 3];
    const uint4 u0 = *(const uint4*)(x + (size_t)p0.x * DD + lane * 8);
    const uint4 u1 = *(const uint4*)(x + (size_t)p1.x * DD + lane * 8);
    const uint4 u2 = *(const uint4*)(x + (size_t)p2.x * DD + lane * 8);
    const uint4 u3 = *(const uint4*)(x + (size_t)p3.x * DD + lane * 8);
    AGG1(u0, __int_as_float(p0.y));
    AGG1(u1, __int_as_float(p1.y));
    AGG1(u2, __int_as_float(p2.y));
    AGG1(u3, __int_as_float(p3.y));
  }
  for (; j < e; ++j) {
    const int2 p = esp[j];
    const uint4 u = *(const uint4*)(x + (size_t)p.x * DD + lane * 8);
    AGG1(u, __int_as_float(p.y));
  }
#undef AGG1
  f32x4* o = (f32x4*)(out + (size_t)node * DD + lane * 8);
  f32x4 o0 = {acc[0], acc[1], acc[2], acc[3]};
  f32x4 o1 = {acc[4], acc[5], acc[6], acc[7]};
  __builtin_nontemporal_store(o0, o);
  __builtin_nontemporal_store(o1, o + 1);
}

extern "C" void kernel_launch(void* const* d_in, const int* in_sizes, int n_in,
                              void* d_out, int out_size, void* d_ws, size_t ws_size,
                              hipStream_t stream) {
  const float* feat     = (const float*)d_in[0];
  const float* weight   = (const float*)d_in[1];
  const float* edge_val = (const float*)d_in[2];
  const int*   edge_src = (const int*)d_in[3];
  const int*   edge_dst = (const int*)d_in[4];
  const int*   mask_idx = (const int*)d_in[5];

  const int n_nodes = in_sizes[0] / DD;   // 50000
  const int n_edges = in_sizes[2];        // 400000
  const int n_mask  = in_sizes[5];        // 15000

  const int n_tiles_m = (n_nodes + BM - 1) / BM;   // 391
  const int m_pad = n_tiles_m * BM;                // 50048

  float* out = (float*)d_out;

  char* base = (char*)d_ws;
  size_t off = 0;
  auto alloc = [&](size_t bytes) {
    void* p = base + off;
    off = (off + bytes + 255) & ~(size_t)255;
    return p;
  };
  u16*   x      = (u16*)alloc((size_t)m_pad * DD * sizeof(u16));   // 51.3 MB
  u16*   wt     = (u16*)alloc((size_t)DD * DD * sizeof(u16));      // 0.5 MB
  // counts + flg contiguous -> single memset
  int*   counts = (int*)alloc((size_t)n_nodes * sizeof(int));
  u8*    flg    = (u8*)alloc((size_t)m_pad);
  const size_t zspan = (size_t)((char*)(flg + m_pad) - (char*)counts);
  int*   offs   = (int*)alloc((size_t)n_nodes * sizeof(int));
  int*   cursor = (int*)alloc((size_t)n_nodes * sizeof(int));
  int*   bsums  = (int*)alloc(SCAN_B * sizeof(int));
  int2*  esp    = (int2*)alloc((size_t)n_edges * sizeof(int2));

  const int nb = (n_nodes + SCAN_B - 1) / SCAN_B;  // 196

  // --- CSR build + row flags ---
  (void)hipMemsetAsync(counts, 0, zspan, stream);
  hist_flag<<<(n_edges + 255) / 256, 256, 0, stream>>>(edge_dst, counts, mask_idx, flg,
                                                       out + (size_t)n_nodes * DD,
                                                       n_edges, n_mask);
  scanA<<<nb, SCAN_B, 0, stream>>>(counts, offs, bsums, n_nodes);
  scanC<<<nb, SCAN_B, 0, stream>>>(offs, bsums, cursor, n_nodes, nb);
  scatter_sort<<<(n_edges + 255) / 256, 256, 0, stream>>>(edge_src, edge_dst, edge_val,
                                                          cursor, esp, n_edges);

  // --- W transpose+convert, then x = bf16(mask(feat)) @ W (B-direct GEMM) ---
  dim3 wg(DD / 64, DD / 64);
  wconv_t<<<wg, 256, 0, stream>>>(weight, wt);
  const int nwg = (DD / BN) * n_tiles_m;   // 1564
  gemm_pipe<<<nwg, 512, 0, stream>>>(feat, wt, x, flg, n_nodes);

  // --- out[node] = sum val * x[src] ---
  aggregate<<<(n_nodes + 3) / 4, 256, 0, stream>>>(x, esp, offs, counts, out, n_nodes);
}

// Round 20
// 200.713 us; speedup vs baseline: 1.0067x; 1.0067x over previous
//
#include <hip/hip_runtime.h>

#define DD 512
#define SCAN_B 256
#define BM 128
#define BN 128
#define BK 32
#define NSTEP 16
typedef unsigned short u16;
typedef unsigned int u32;
typedef unsigned char u8;

typedef __attribute__((ext_vector_type(8))) __bf16 bf16v8;
typedef __attribute__((ext_vector_type(2))) __bf16 bf16v2;
typedef __attribute__((ext_vector_type(4))) float f32x4;

// native RNE f32->bf16 (v_cvt_pk_bf16_f32 for pairs)
__device__ __forceinline__ u32 pk2(float a, float b) {
  bf16v2 v;
  v[0] = (__bf16)a;
  v[1] = (__bf16)b;
  return __builtin_bit_cast(u32, v);
}
__device__ __forceinline__ u16 f2bf(float f) {
  return __builtin_bit_cast(u16, (__bf16)f);
}
__device__ __forceinline__ float bf2f(u32 h) {
  return __builtin_bit_cast(float, h << 16);
}

// counted-vmcnt barrier: keep the N newest VMEM ops in flight across it
#define BAR_N(N)                                                        \
  do {                                                                  \
    __builtin_amdgcn_sched_barrier(0);                                  \
    asm volatile("s_waitcnt vmcnt(" #N ") lgkmcnt(0)\n\ts_barrier" ::: "memory"); \
  } while (0)

// ---------------- W[k][n] f32 -> Wt[n][k] bf16 (LDS-tiled transpose) ----------------
__global__ __launch_bounds__(256) void wconv_t(const float* __restrict__ W,
                                               u16* __restrict__ Wt) {
  __shared__ float sm[64][65];
  const int bx = blockIdx.x;   // k tile
  const int by = blockIdx.y;   // n tile
  const int t = threadIdx.x;
  const int r = t >> 6;
  const int c = t & 63;
#pragma unroll
  for (int i = 0; i < 64; i += 4)
    sm[i + r][c] = W[(size_t)(bx * 64 + i + r) * DD + by * 64 + c];
  __syncthreads();
#pragma unroll
  for (int i = 0; i < 64; i += 4) {
    const int n = by * 64 + i + r;
    const int k = bx * 64 + c;
    Wt[(size_t)n * DD + k] = f2bf(sm[c][i + r]);
  }
}

// ---- B-direct GEMM, r20: + B register double-buffer (B(t+1) loaded at step t) ----
// BM=128 x BN=128 x BK=32, 512 threads (8 waves, 2x4, 64x32 tile/wave), 16 steps.
// B: direct per-lane L2 loads from Wt (512 KB, L2-hot), double-buffered in regs
//    -> one full step (~500cy) of flight; bfr[t&1] is retired for free by the
//    previous step's ds_write vmcnt (in-order retirement).
// A: r13 staging (f32 -> mask -> cvt_pk -> ds_write, XOR swizzle), 3-parity
//    prefetch, 2-buf LDS (16 KB total -> high occupancy).
// Barrier fences lgkm only (no gload_lds); BAR_N(4) keeps B(t+1)+A(t+2) in flight.
__global__ __launch_bounds__(512, 4) void gemm_pipe(const float* __restrict__ A,
                                                    const u16* __restrict__ Bt,
                                                    u16* __restrict__ X,
                                                    const u8* __restrict__ flg, int M) {
  __shared__ __align__(16) u16 ldsA[2][BM * BK];   // 2 x 8 KB
  const int tid = threadIdx.x;
  const int lane = tid & 63;
  const int w = tid >> 6;        // 0..7
  const int wm = w >> 2;         // 0..1  (64 rows)
  const int wn = w & 3;          // 0..3  (32 cols)

  // bijective XCD swizzle (ERRATA #11): units 4s..4s+3 = stripe s's col tiles
  const int nwg = gridDim.x;
  const int b = blockIdx.x;
  const int xcd = b & 7, jj = b >> 3;
  const int q = nwg >> 3, r_ = nwg & 7;
  const int unit = (xcd < r_ ? xcd * (q + 1) : r_ * (q + 1) + (xcd - r_) * q) + jj;
  const int row0 = (unit >> 2) * BM;
  const int colB = (unit & 3) * BN;

  const int lr = lane & 15;
  const int kg = lane >> 4;

  f32x4 acc[4][2] = {};

  // A staging (r13 verified): thread t stages chunk t (row=t>>2, slot kc=t&3,
  // global chunk gk = kc ^ ((row>>1)&3))
  const int arow = tid >> 2;
  const int agk = (tid & 3) ^ ((arow >> 1) & 3);
  int ar = row0 + arow;
  if (ar >= M) ar = M - 1;            // pad rows: garbage x, never read
  const float* gA = A + (size_t)ar * DD + agk * 8;
  const int laoff = tid * 8;
  const u32 akeep = flg[ar] ? 0u : 0xFFFFFFFFu;   // masked row -> zero pack

  // B-direct: per-lane fragment pointers into L2-resident Wt
  const u16* gB0 = Bt + (size_t)(colB + wn * 32 + lr) * DD + kg * 8;
  const u16* gB1 = Bt + (size_t)(colB + wn * 32 + 16 + lr) * DD + kg * 8;

  f32x4 rP[3][2];     // A reg prefetch, 3 parities (static idx after full unroll)
  bf16v8 bfr[2][2];   // B reg double-buffer (static idx after full unroll)

  // ---- prologue: load B(0); A(0),A(1); stage A(0); barrier ----
  bfr[0][0] = *(const bf16v8*)(gB0);
  bfr[0][1] = *(const bf16v8*)(gB1);
  rP[0][0] = *(const f32x4*)(gA);
  rP[0][1] = *(const f32x4*)(gA + 4);
  rP[1][0] = *(const f32x4*)(gA + BK);
  rP[1][1] = *(const f32x4*)(gA + BK + 4);
  {
    uint4 pk;
    pk.x = pk2(rP[0][0].x, rP[0][0].y) & akeep;
    pk.y = pk2(rP[0][0].z, rP[0][0].w) & akeep;
    pk.z = pk2(rP[0][1].x, rP[0][1].y) & akeep;
    pk.w = pk2(rP[0][1].z, rP[0][1].w) & akeep;
    *(uint4*)&ldsA[0][laoff] = pk;   // implicit vmcnt retires B(0),A(0); keeps A(1)
  }
  BAR_N(2);   // A(1)x2 stays in flight

#pragma unroll
  for (int t = 0; t < NSTEP; ++t) {
    // issue B(t+1) (full step of flight) and A(t+2) prefetch
    if (t + 1 < NSTEP) {
      bfr[(t + 1) & 1][0] = *(const bf16v8*)(gB0 + (t + 1) * BK);
      bfr[(t + 1) & 1][1] = *(const bf16v8*)(gB1 + (t + 1) * BK);
    }
    if (t + 2 < NSTEP) {
      rP[(t + 2) % 3][0] = *(const f32x4*)(gA + (t + 2) * BK);
      rP[(t + 2) % 3][1] = *(const f32x4*)(gA + (t + 2) * BK + 4);
    }

    // A fragments from current LDS buffer; bfr[t&1] already resident (retired
    // by last step's ds_write wait -- no vmcnt on the MFMA path)
    bf16v8 af[4];
#pragma unroll
    for (int m = 0; m < 4; ++m) {
      const int row = wm * 64 + m * 16 + lr;
      const int kc = kg ^ ((row >> 1) & 3);
      af[m] = *(const bf16v8*)&ldsA[t & 1][row * BK + kc * 8];
    }
#pragma unroll
    for (int m = 0; m < 4; ++m)
#pragma unroll
      for (int n = 0; n < 2; ++n)
        acc[m][n] = __builtin_amdgcn_mfma_f32_16x16x32_bf16(af[m], bfr[t & 1][n], acc[m][n], 0, 0, 0);

    // stage A(t+1); implicit vmcnt retires A(t+1) loads AND (in-order) B(t)
    if (t + 1 < NSTEP) {
      const f32x4 p0 = rP[(t + 1) % 3][0];
      const f32x4 p1 = rP[(t + 1) % 3][1];
      uint4 pk;
      pk.x = pk2(p0.x, p0.y) & akeep;
      pk.y = pk2(p0.z, p0.w) & akeep;
      pk.z = pk2(p1.x, p1.y) & akeep;
      pk.w = pk2(p1.z, p1.w) & akeep;
      *(uint4*)&ldsA[(t + 1) & 1][laoff] = pk;
    }

    // barrier (lgkm is the real fence; vmcnt(4) keeps B(t+1)x2 + A(t+2)x2)
    if (t < NSTEP - 2)      BAR_N(4);
    else if (t < NSTEP - 1) BAR_N(0);
    // t == NSTEP-1: no barrier (epilogue uses regs only)
  }

  // C/D layout: col = lane&15, row = (lane>>4)*4 + reg
  const int crow = (lane >> 4) * 4;
  const int ccol = lane & 15;
#pragma unroll
  for (int m = 0; m < 4; ++m) {
    const int rowb = row0 + wm * 64 + m * 16 + crow;
#pragma unroll
    for (int n = 0; n < 2; ++n) {
      const int col = colB + wn * 32 + n * 16 + ccol;
#pragma unroll
      for (int r = 0; r < 4; ++r)
        X[(size_t)(rowb + r) * DD + col] = f2bf(acc[m][n][r]);
    }
  }
}

// ---- hist + flag_build fused (grid covers n_edges >= n_mask) ----
__global__ __launch_bounds__(256) void hist_flag(const int* __restrict__ dst,
                                                 int* __restrict__ counts,
                                                 const int* __restrict__ mask,
                                                 u8* __restrict__ flg,
                                                 float* __restrict__ out_tail,
                                                 int n, int nm) {
  const int i = blockIdx.x * blockDim.x + threadIdx.x;
  if (i < n) atomicAdd(&counts[dst[i]], 1);
  if (i < nm) {
    const int r = mask[i];
    flg[r] = 1;
    out_tail[i] = (float)r;
  }
}

__global__ __launch_bounds__(SCAN_B) void scanA(const int* __restrict__ counts,
                                                int* __restrict__ lscan,
                                                int* __restrict__ blockSums, int n) {
  __shared__ int sm[SCAN_B];
  const int t = threadIdx.x;
  const int i = blockIdx.x * SCAN_B + t;
  const int v = (i < n) ? counts[i] : 0;
  sm[t] = v;
  __syncthreads();
  for (int off = 1; off < SCAN_B; off <<= 1) {
    int add = (t >= off) ? sm[t - off] : 0;
    __syncthreads();
    sm[t] += add;
    __syncthreads();
  }
  if (i < n) lscan[i] = sm[t] - v;
  if (t == SCAN_B - 1) blockSums[blockIdx.x] = sm[t];
}

// scanC: each block re-scans the (<=256) block sums locally for its base,
// then finalizes offsets + cursor (scanB folded in).
__global__ __launch_bounds__(SCAN_B) void scanC(int* __restrict__ lscan,
                                                const int* __restrict__ blockSums,
                                                int* __restrict__ cursor, int n, int nb) {
  __shared__ int sm[SCAN_B];
  const int t = threadIdx.x;
  const int v = (t < nb) ? blockSums[t] : 0;
  sm[t] = v;
  __syncthreads();
  for (int off = 1; off < SCAN_B; off <<= 1) {
    int add = (t >= off) ? sm[t - off] : 0;
    __syncthreads();
    sm[t] += add;
    __syncthreads();
  }
  const int base = sm[blockIdx.x] - ((blockIdx.x < nb) ? blockSums[blockIdx.x] : 0);
  const int i = blockIdx.x * SCAN_B + t;
  if (i < n) {
    const int o = lscan[i] + base;
    lscan[i] = o;
    cursor[i] = o;
  }
}

// scatter into dst-sorted order; edge payload packed as (src, val) int2
__global__ __launch_bounds__(256) void scatter_sort(const int* __restrict__ src,
                                                    const int* __restrict__ dst,
                                                    const float* __restrict__ ev,
                                                    int* __restrict__ cursor,
                                                    int2* __restrict__ esp, int n) {
  const int i = blockIdx.x * blockDim.x + threadIdx.x;
  if (i < n) {
    const int pos = atomicAdd(&cursor[dst[i]], 1);
    esp[pos] = make_int2(src[i], __float_as_int(ev[i]));
  }
}

// ------------- per-node accumulation from bf16 x, f32 accumulate -------------
// one wave per node; 8x-unrolled edge loop (fabric-BW-bound per r15/r16 tests)
__global__ __launch_bounds__(256) void aggregate(const u16* __restrict__ x,
                                                 const int2* __restrict__ esp,
                                                 const int* __restrict__ offsets,
                                                 const int* __restrict__ counts,
                                                 float* __restrict__ out, int n_nodes) {
  const int node = blockIdx.x * 4 + (threadIdx.x >> 6);
  if (node >= n_nodes) return;
  const int lane = threadIdx.x & 63;
  const int b = offsets[node];
  const int e = b + counts[node];
  float acc[8] = {};
  int j = b;
#define AGG1(U, V)                                      \
  do {                                                  \
    acc[0] = fmaf(V, bf2f(U.x & 0xffffu), acc[0]);      \
    acc[1] = fmaf(V, bf2f(U.x >> 16),     acc[1]);      \
    acc[2] = fmaf(V, bf2f(U.y & 0xffffu), acc[2]);      \
    acc[3] = fmaf(V, bf2f(U.y >> 16),     acc[3]);      \
    acc[4] = fmaf(V, bf2f(U.z & 0xffffu), acc[4]);      \
    acc[5] = fmaf(V, bf2f(U.z >> 16),     acc[5]);      \
    acc[6] = fmaf(V, bf2f(U.w & 0xffffu), acc[6]);      \
    acc[7] = fmaf(V, bf2f(U.w >> 16),     acc[7]);      \
  } while (0)
  for (; j + 8 <= e; j += 8) {
    int2 p[8];
    uint4 u[8];
#pragma unroll
    for (int k = 0; k < 8; ++k) p[k] = esp[j + k];
#pragma unroll
    for (int k = 0; k < 8; ++k)
      u[k] = *(const uint4*)(x + (size_t)p[k].x * DD + lane * 8);
#pragma unroll
    for (int k = 0; k < 8; ++k) AGG1(u[k], __int_as_float(p[k].y));
  }
  for (; j + 4 <= e; j += 4) {
    const int2 p0 = esp[j], p1 = esp[j + 1], p2 = esp[j + 2], p3 = esp[j + 3];
    const uint4 u0 = *(const uint4*)(x + (size_t)p0.x * DD + lane * 8);
    const uint4 u1 = *(const uint4*)(x + (size_t)p1.x * DD + lane * 8);
    const uint4 u2 = *(const uint4*)(x + (size_t)p2.x * DD + lane * 8);
    const uint4 u3 = *(const uint4*)(x + (size_t)p3.x * DD + lane * 8);
    AGG1(u0, __int_as_float(p0.y));
    AGG1(u1, __int_as_float(p1.y));
    AGG1(u2, __int_as_float(p2.y));
    AGG1(u3, __int_as_float(p3.y));
  }
  for (; j < e; ++j) {
    const int2 p = esp[j];
    const uint4 u = *(const uint4*)(x + (size_t)p.x * DD + lane * 8);
    AGG1(u, __int_as_float(p.y));
  }
#undef AGG1
  f32x4* o = (f32x4*)(out + (size_t)node * DD + lane * 8);
  f32x4 o0 = {acc[0], acc[1], acc[2], acc[3]};
  f32x4 o1 = {acc[4], acc[5], acc[6], acc[7]};
  __builtin_nontemporal_store(o0, o);
  __builtin_nontemporal_store(o1, o + 1);
}

extern "C" void kernel_launch(void* const* d_in, const int* in_sizes, int n_in,
                              void* d_out, int out_size, void* d_ws, size_t ws_size,
                              hipStream_t stream) {
  const float* feat     = (const float*)d_in[0];
  const float* weight   = (const float*)d_in[1];
  const float* edge_val = (const float*)d_in[2];
  const int*   edge_src = (const int*)d_in[3];
  const int*   edge_dst = (const int*)d_in[4];
  const int*   mask_idx = (const int*)d_in[5];

  const int n_nodes = in_sizes[0] / DD;   // 50000
  const int n_edges = in_sizes[2];        // 400000
  const int n_mask  = in_sizes[5];        // 15000

  const int n_tiles_m = (n_nodes + BM - 1) / BM;   // 391
  const int m_pad = n_tiles_m * BM;                // 50048

  float* out = (float*)d_out;

  char* base = (char*)d_ws;
  size_t off = 0;
  auto alloc = [&](size_t bytes) {
    void* p = base + off;
    off = (off + bytes + 255) & ~(size_t)255;
    return p;
  };
  u16*   x      = (u16*)alloc((size_t)m_pad * DD * sizeof(u16));   // 51.3 MB
  u16*   wt     = (u16*)alloc((size_t)DD * DD * sizeof(u16));      // 0.5 MB
  // counts + flg contiguous -> single memset
  int*   counts = (int*)alloc((size_t)n_nodes * sizeof(int));
  u8*    flg    = (u8*)alloc((size_t)m_pad);
  const size_t zspan = (size_t)((char*)(flg + m_pad) - (char*)counts);
  int*   offs   = (int*)alloc((size_t)n_nodes * sizeof(int));
  int*   cursor = (int*)alloc((size_t)n_nodes * sizeof(int));
  int*   bsums  = (int*)alloc(SCAN_B * sizeof(int));
  int2*  esp    = (int2*)alloc((size_t)n_edges * sizeof(int2));

  const int nb = (n_nodes + SCAN_B - 1) / SCAN_B;  // 196

  // --- CSR build + row flags ---
  (void)hipMemsetAsync(counts, 0, zspan, stream);
  hist_flag<<<(n_edges + 255) / 256, 256, 0, stream>>>(edge_dst, counts, mask_idx, flg,
                                                       out + (size_t)n_nodes * DD,
                                                       n_edges, n_mask);
  scanA<<<nb, SCAN_B, 0, stream>>>(counts, offs, bsums, n_nodes);
  scanC<<<nb, SCAN_B, 0, stream>>>(offs, bsums, cursor, n_nodes, nb);
  scatter_sort<<<(n_edges + 255) / 256, 256, 0, stream>>>(edge_src, edge_dst, edge_val,
                                                          cursor, esp, n_edges);

  // --- W transpose+convert, then x = bf16(mask(feat)) @ W (B-direct GEMM) ---
  dim3 wg(DD / 64, DD / 64);
  wconv_t<<<wg, 256, 0, stream>>>(weight, wt);
  const int nwg = (DD / BN) * n_tiles_m;   // 1564
  gemm_pipe<<<nwg, 512, 0, stream>>>(feat, wt, x, flg, n_nodes);

  // --- out[node] = sum val * x[src] ---
  aggregate<<<(n_nodes + 3) / 4, 256, 0, stream>>>(x, esp, offs, counts, out, n_nodes);
}

// Round 21
// 171.861 us; speedup vs baseline: 1.1757x; 1.1679x over previous
//
#include <hip/hip_runtime.h>

#define DD 512
#define SCAN_B 256
#define BM 128
#define BN 128
#define BK 64
#define NSTEP 8
typedef unsigned short u16;
typedef unsigned int u32;
typedef unsigned char u8;

typedef __attribute__((ext_vector_type(8))) __bf16 bf16v8;
typedef __attribute__((ext_vector_type(2))) __bf16 bf16v2;
typedef __attribute__((ext_vector_type(4))) float f32x4;

// native RNE f32->bf16 (v_cvt_pk_bf16_f32 for pairs)
__device__ __forceinline__ u32 pk2(float a, float b) {
  bf16v2 v;
  v[0] = (__bf16)a;
  v[1] = (__bf16)b;
  return __builtin_bit_cast(u32, v);
}
__device__ __forceinline__ u16 f2bf(float f) {
  return __builtin_bit_cast(u16, (__bf16)f);
}
__device__ __forceinline__ float bf2f(u32 h) {
  return __builtin_bit_cast(float, h << 16);
}

typedef const __attribute__((address_space(1))) void* gptr_t;
typedef __attribute__((address_space(3))) void* lptr_t;
__device__ __forceinline__ void gload_lds16(const void* g, void* l) {
  __builtin_amdgcn_global_load_lds((gptr_t)g, (lptr_t)l, 16, 0, 0);
}

// counted-vmcnt barrier: keep the N newest VMEM ops in flight across it
#define BAR_N(N)                                                        \
  do {                                                                  \
    __builtin_amdgcn_sched_barrier(0);                                  \
    asm volatile("s_waitcnt vmcnt(" #N ") lgkmcnt(0)\n\ts_barrier" ::: "memory"); \
  } while (0)

// ---------------- W[k][n] f32 -> Wt[n][k] bf16 (LDS-tiled transpose) ----------------
__global__ __launch_bounds__(256) void wconv_t(const float* __restrict__ W,
                                               u16* __restrict__ Wt) {
  __shared__ float sm[64][65];
  const int bx = blockIdx.x;   // k tile
  const int by = blockIdx.y;   // n tile
  const int t = threadIdx.x;
  const int r = t >> 6;
  const int c = t & 63;
#pragma unroll
  for (int i = 0; i < 64; i += 4)
    sm[i + r][c] = W[(size_t)(bx * 64 + i + r) * DD + by * 64 + c];
  __syncthreads();
#pragma unroll
  for (int i = 0; i < 64; i += 4) {
    const int n = by * 64 + i + r;
    const int k = bx * 64 + c;
    Wt[(size_t)n * DD + k] = f2bf(sm[c][i + r]);
  }
}

// ---- BK=64 pipelined fused GEMM (r16/r18 verified best) ----
// BM=128 x BN=128 x BK=64, 512 threads (8 waves, 2x4, 64x32 tile/wave), 8 K-steps.
// A: 3-parity reg prefetch (f32 load -> mask -> cvt_pk -> ds_write), 2-buf LDS.
// B: gload_lds 1-step ahead (L2-resident Wt, coalesced), 2-buf LDS. XOR swizzle.
// Counted vmcnt(4) keeps A(t+2)x4 in flight across the barrier.
// XCD-aware bijective swizzle: stripe's 4 col-tiles on one XCD (FETCH 201->55MB).
__global__ __launch_bounds__(512, 4) void gemm_pipe(const float* __restrict__ A,
                                                    const u16* __restrict__ Bt,
                                                    u16* __restrict__ X,
                                                    const u8* __restrict__ flg, int M) {
  __shared__ __align__(16) u16 ldsA[2][BM * BK];   // 2 x 16 KB
  __shared__ __align__(16) u16 ldsB[2][BN * BK];   // 2 x 16 KB
  const int tid = threadIdx.x;
  const int lane = tid & 63;
  const int w = tid >> 6;        // 0..7
  const int wm = w >> 2;         // 0..1  (64 rows)
  const int wn = w & 3;          // 0..3  (32 cols)

  // bijective XCD swizzle (ERRATA #11): units 4s..4s+3 = stripe s's col tiles
  const int nwg = gridDim.x;
  const int b = blockIdx.x;
  const int xcd = b & 7, jj = b >> 3;
  const int q = nwg >> 3, r_ = nwg & 7;
  const int unit = (xcd < r_ ? xcd * (q + 1) : r_ * (q + 1) + (xcd - r_) * q) + jj;
  const int row0 = (unit >> 2) * BM;
  const int colB = (unit & 3) * BN;

  const int lr = lane & 15;
  const int kg = lane >> 4;

  f32x4 acc[4][2] = {};

  // A staging: thread t stages chunks t (row=t>>3) and t+512 (row+64); slot s=t&7,
  // global chunk g = s ^ (row&7)
  const int arow0 = tid >> 3;
  const int as = tid & 7;
  const int ag = as ^ (arow0 & 7);
  int ar0 = row0 + arow0;      if (ar0 >= M) ar0 = M - 1;
  int ar1 = row0 + arow0 + 64; if (ar1 >= M) ar1 = M - 1;
  const float* gA0 = A + (size_t)ar0 * DD + ag * 8;
  const float* gA1 = A + (size_t)ar1 * DD + ag * 8;
  const int la0 = arow0 * BK + as * 8;
  const int la1 = (arow0 + 64) * BK + as * 8;
  const u32 akeep0 = flg[ar0] ? 0u : 0xFFFFFFFFu;
  const u32 akeep1 = flg[ar1] ? 0u : 0xFFFFFFFFu;

  // B staging: chunks tid, tid+512; linear LDS dest, pre-swizzled global src
  const int bcol0 = tid >> 3, bs = tid & 7;
  const int bg = bs ^ (bcol0 & 7);
  const u16* gB0 = Bt + (size_t)(colB + bcol0) * DD + bg * 8;
  const u16* gB1 = Bt + (size_t)(colB + bcol0 + 64) * DD + bg * 8;
  const int lb0 = tid * 8, lb1 = (tid + 512) * 8;

  f32x4 rP[3][4];   // A reg prefetch, 3 parities x 4 (static idx after unroll)

  // ---- prologue: B(0); A(0),A(1); stage A(0); barrier ----
  gload_lds16(gB0, &ldsB[0][lb0]);
  gload_lds16(gB1, &ldsB[0][lb1]);
#pragma unroll
  for (int p = 0; p < 2; ++p) {
    rP[p][0] = *(const f32x4*)(gA0 + p * BK);
    rP[p][1] = *(const f32x4*)(gA0 + p * BK + 4);
    rP[p][2] = *(const f32x4*)(gA1 + p * BK);
    rP[p][3] = *(const f32x4*)(gA1 + p * BK + 4);
  }
  {
    uint4 w0, w1;
    w0.x = pk2(rP[0][0].x, rP[0][0].y) & akeep0;
    w0.y = pk2(rP[0][0].z, rP[0][0].w) & akeep0;
    w0.z = pk2(rP[0][1].x, rP[0][1].y) & akeep0;
    w0.w = pk2(rP[0][1].z, rP[0][1].w) & akeep0;
    w1.x = pk2(rP[0][2].x, rP[0][2].y) & akeep1;
    w1.y = pk2(rP[0][2].z, rP[0][2].w) & akeep1;
    w1.z = pk2(rP[0][3].x, rP[0][3].y) & akeep1;
    w1.w = pk2(rP[0][3].z, rP[0][3].w) & akeep1;
    *(uint4*)&ldsA[0][la0] = w0;
    *(uint4*)&ldsA[0][la1] = w1;
  }
  BAR_N(4);   // drain B(0); keep A(1)x4 in flight

#pragma unroll
  for (int t = 0; t < NSTEP; ++t) {
    if (t + 1 < NSTEP) {
      gload_lds16(gB0 + (t + 1) * BK, &ldsB[(t + 1) & 1][lb0]);
      gload_lds16(gB1 + (t + 1) * BK, &ldsB[(t + 1) & 1][lb1]);
    }
    if (t + 2 < NSTEP) {
      rP[(t + 2) % 3][0] = *(const f32x4*)(gA0 + (t + 2) * BK);
      rP[(t + 2) % 3][1] = *(const f32x4*)(gA0 + (t + 2) * BK + 4);
      rP[(t + 2) % 3][2] = *(const f32x4*)(gA1 + (t + 2) * BK);
      rP[(t + 2) % 3][3] = *(const f32x4*)(gA1 + (t + 2) * BK + 4);
    }

#pragma unroll
    for (int h = 0; h < 2; ++h) {
      bf16v8 af[4], bfr[2];
      const int c = h * 4 + kg;
#pragma unroll
      for (int m = 0; m < 4; ++m) {
        const int row = wm * 64 + m * 16 + lr;
        const int s = c ^ (row & 7);
        af[m] = *(const bf16v8*)&ldsA[t & 1][row * BK + s * 8];
      }
#pragma unroll
      for (int n = 0; n < 2; ++n) {
        const int col = wn * 32 + n * 16 + lr;
        const int s = c ^ (col & 7);
        bfr[n] = *(const bf16v8*)&ldsB[t & 1][col * BK + s * 8];
      }
#pragma unroll
      for (int m = 0; m < 4; ++m)
#pragma unroll
        for (int n = 0; n < 2; ++n)
          acc[m][n] = __builtin_amdgcn_mfma_f32_16x16x32_bf16(af[m], bfr[n], acc[m][n], 0, 0, 0);
    }

    if (t + 1 < NSTEP) {
      const f32x4 p0 = rP[(t + 1) % 3][0], p1 = rP[(t + 1) % 3][1];
      const f32x4 p2 = rP[(t + 1) % 3][2], p3 = rP[(t + 1) % 3][3];
      uint4 w0, w1;
      w0.x = pk2(p0.x, p0.y) & akeep0;
      w0.y = pk2(p0.z, p0.w) & akeep0;
      w0.z = pk2(p1.x, p1.y) & akeep0;
      w0.w = pk2(p1.z, p1.w) & akeep0;
      w1.x = pk2(p2.x, p2.y) & akeep1;
      w1.y = pk2(p2.z, p2.w) & akeep1;
      w1.z = pk2(p3.x, p3.y) & akeep1;
      w1.w = pk2(p3.z, p3.w) & akeep1;
      *(uint4*)&ldsA[(t + 1) & 1][la0] = w0;
      *(uint4*)&ldsA[(t + 1) & 1][la1] = w1;
    }

    if (t < NSTEP - 2)      BAR_N(4);
    else if (t < NSTEP - 1) BAR_N(0);
  }

  // C/D layout: col = lane&15, row = (lane>>4)*4 + reg
  const int crow = (lane >> 4) * 4;
  const int ccol = lane & 15;
#pragma unroll
  for (int m = 0; m < 4; ++m) {
    const int rowb = row0 + wm * 64 + m * 16 + crow;
#pragma unroll
    for (int n = 0; n < 2; ++n) {
      const int col = colB + wn * 32 + n * 16 + ccol;
#pragma unroll
      for (int r = 0; r < 4; ++r)
        X[(size_t)(rowb + r) * DD + col] = f2bf(acc[m][n][r]);
    }
  }
}

// ---- hist + flag_build fused (grid covers n_edges >= n_mask) ----
__global__ __launch_bounds__(256) void hist_flag(const int* __restrict__ dst,
                                                 int* __restrict__ counts,
                                                 const int* __restrict__ mask,
                                                 u8* __restrict__ flg,
                                                 float* __restrict__ out_tail,
                                                 int n, int nm) {
  const int i = blockIdx.x * blockDim.x + threadIdx.x;
  if (i < n) atomicAdd(&counts[dst[i]], 1);
  if (i < nm) {
    const int r = mask[i];
    flg[r] = 1;
    out_tail[i] = (float)r;
  }
}

__global__ __launch_bounds__(SCAN_B) void scanA(const int* __restrict__ counts,
                                                int* __restrict__ lscan,
                                                int* __restrict__ blockSums, int n) {
  __shared__ int sm[SCAN_B];
  const int t = threadIdx.x;
  const int i = blockIdx.x * SCAN_B + t;
  const int v = (i < n) ? counts[i] : 0;
  sm[t] = v;
  __syncthreads();
  for (int off = 1; off < SCAN_B; off <<= 1) {
    int add = (t >= off) ? sm[t - off] : 0;
    __syncthreads();
    sm[t] += add;
    __syncthreads();
  }
  if (i < n) lscan[i] = sm[t] - v;
  if (t == SCAN_B - 1) blockSums[blockIdx.x] = sm[t];
}

// scanC: each block re-scans the (<=256) block sums locally for its base,
// then finalizes offsets + cursor (scanB folded in).
__global__ __launch_bounds__(SCAN_B) void scanC(int* __restrict__ lscan,
                                                const int* __restrict__ blockSums,
                                                int* __restrict__ cursor, int n, int nb) {
  __shared__ int sm[SCAN_B];
  const int t = threadIdx.x;
  const int v = (t < nb) ? blockSums[t] : 0;
  sm[t] = v;
  __syncthreads();
  for (int off = 1; off < SCAN_B; off <<= 1) {
    int add = (t >= off) ? sm[t - off] : 0;
    __syncthreads();
    sm[t] += add;
    __syncthreads();
  }
  const int base = sm[blockIdx.x] - ((blockIdx.x < nb) ? blockSums[blockIdx.x] : 0);
  const int i = blockIdx.x * SCAN_B + t;
  if (i < n) {
    const int o = lscan[i] + base;
    lscan[i] = o;
    cursor[i] = o;
  }
}

// scatter into dst-sorted order; edge payload packed as (src, val) int2
__global__ __launch_bounds__(256) void scatter_sort(const int* __restrict__ src,
                                                    const int* __restrict__ dst,
                                                    const float* __restrict__ ev,
                                                    int* __restrict__ cursor,
                                                    int2* __restrict__ esp, int n) {
  const int i = blockIdx.x * blockDim.x + threadIdx.x;
  if (i < n) {
    const int pos = atomicAdd(&cursor[dst[i]], 1);
    esp[pos] = make_int2(src[i], __float_as_int(ev[i]));
  }
}

// ------------- per-node accumulation from bf16 x, f32 accumulate -------------
// one wave per node; 8x-unrolled edge loop (fabric-BW-bound per r15/r16 tests)
__global__ __launch_bounds__(256) void aggregate(const u16* __restrict__ x,
                                                 const int2* __restrict__ esp,
                                                 const int* __restrict__ offsets,
                                                 const int* __restrict__ counts,
                                                 float* __restrict__ out, int n_nodes) {
  const int node = blockIdx.x * 4 + (threadIdx.x >> 6);
  if (node >= n_nodes) return;
  const int lane = threadIdx.x & 63;
  const int b = offsets[node];
  const int e = b + counts[node];
  float acc[8] = {};
  int j = b;
#define AGG1(U, V)                                      \
  do {                                                  \
    acc[0] = fmaf(V, bf2f(U.x & 0xffffu), acc[0]);      \
    acc[1] = fmaf(V, bf2f(U.x >> 16),     acc[1]);      \
    acc[2] = fmaf(V, bf2f(U.y & 0xffffu), acc[2]);      \
    acc[3] = fmaf(V, bf2f(U.y >> 16),     acc[3]);      \
    acc[4] = fmaf(V, bf2f(U.z & 0xffffu), acc[4]);      \
    acc[5] = fmaf(V, bf2f(U.z >> 16),     acc[5]);      \
    acc[6] = fmaf(V, bf2f(U.w & 0xffffu), acc[6]);      \
    acc[7] = fmaf(V, bf2f(U.w >> 16),     acc[7]);      \
  } while (0)
  for (; j + 8 <= e; j += 8) {
    int2 p[8];
    uint4 u[8];
#pragma unroll
    for (int k = 0; k < 8; ++k) p[k] = esp[j + k];
#pragma unroll
    for (int k = 0; k < 8; ++k)
      u[k] = *(const uint4*)(x + (size_t)p[k].x * DD + lane * 8);
#pragma unroll
    for (int k = 0; k < 8; ++k) AGG1(u[k], __int_as_float(p[k].y));
  }
  for (; j + 4 <= e; j += 4) {
    const int2 p0 = esp[j], p1 = esp[j + 1], p2 = esp[j + 2], p3 = esp[j + 3];
    const uint4 u0 = *(const uint4*)(x + (size_t)p0.x * DD + lane * 8);
    const uint4 u1 = *(const uint4*)(x + (size_t)p1.x * DD + lane * 8);
    const uint4 u2 = *(const uint4*)(x + (size_t)p2.x * DD + lane * 8);
    const uint4 u3 = *(const uint4*)(x + (size_t)p3.x * DD + lane * 8);
    AGG1(u0, __int_as_float(p0.y));
    AGG1(u1, __int_as_float(p1.y));
    AGG1(u2, __int_as_float(p2.y));
    AGG1(u3, __int_as_float(p3.y));
  }
  for (; j < e; ++j) {
    const int2 p = esp[j];
    const uint4 u = *(const uint4*)(x + (size_t)p.x * DD + lane * 8);
    AGG1(u, __int_as_float(p.y));
  }
#undef AGG1
  f32x4* o = (f32x4*)(out + (size_t)node * DD + lane * 8);
  f32x4 o0 = {acc[0], acc[1], acc[2], acc[3]};
  f32x4 o1 = {acc[4], acc[5], acc[6], acc[7]};
  __builtin_nontemporal_store(o0, o);
  __builtin_nontemporal_store(o1, o + 1);
}

extern "C" void kernel_launch(void* const* d_in, const int* in_sizes, int n_in,
                              void* d_out, int out_size, void* d_ws, size_t ws_size,
                              hipStream_t stream) {
  const float* feat     = (const float*)d_in[0];
  const float* weight   = (const float*)d_in[1];
  const float* edge_val = (const float*)d_in[2];
  const int*   edge_src = (const int*)d_in[3];
  const int*   edge_dst = (const int*)d_in[4];
  const int*   mask_idx = (const int*)d_in[5];

  const int n_nodes = in_sizes[0] / DD;   // 50000
  const int n_edges = in_sizes[2];        // 400000
  const int n_mask  = in_sizes[5];        // 15000

  const int n_tiles_m = (n_nodes + BM - 1) / BM;   // 391
  const int m_pad = n_tiles_m * BM;                // 50048

  float* out = (float*)d_out;

  char* base = (char*)d_ws;
  size_t off = 0;
  auto alloc = [&](size_t bytes) {
    void* p = base + off;
    off = (off + bytes + 255) & ~(size_t)255;
    return p;
  };
  u16*   x      = (u16*)alloc((size_t)m_pad * DD * sizeof(u16));   // 51.3 MB
  u16*   wt     = (u16*)alloc((size_t)DD * DD * sizeof(u16));      // 0.5 MB
  // counts + flg contiguous -> single memset
  int*   counts = (int*)alloc((size_t)n_nodes * sizeof(int));
  u8*    flg    = (u8*)alloc((size_t)m_pad);
  const size_t zspan = (size_t)((char*)(flg + m_pad) - (char*)counts);
  int*   offs   = (int*)alloc((size_t)n_nodes * sizeof(int));
  int*   cursor = (int*)alloc((size_t)n_nodes * sizeof(int));
  int*   bsums  = (int*)alloc(SCAN_B * sizeof(int));
  int2*  esp    = (int2*)alloc((size_t)n_edges * sizeof(int2));

  const int nb = (n_nodes + SCAN_B - 1) / SCAN_B;  // 196

  // --- CSR build + row flags ---
  (void)hipMemsetAsync(counts, 0, zspan, stream);
  hist_flag<<<(n_edges + 255) / 256, 256, 0, stream>>>(edge_dst, counts, mask_idx, flg,
                                                       out + (size_t)n_nodes * DD,
                                                       n_edges, n_mask);
  scanA<<<nb, SCAN_B, 0, stream>>>(counts, offs, bsums, n_nodes);
  scanC<<<nb, SCAN_B, 0, stream>>>(offs, bsums, cursor, n_nodes, nb);
  scatter_sort<<<(n_edges + 255) / 256, 256, 0, stream>>>(edge_src, edge_dst, edge_val,
                                                          cursor, esp, n_edges);

  // --- W transpose+convert, then x = bf16(mask(feat)) @ W (BK=64 fused GEMM) ---
  dim3 wg(DD / 64, DD / 64);
  wconv_t<<<wg, 256, 0, stream>>>(weight, wt);
  const int nwg = (DD / BN) * n_tiles_m;   // 1564
  gemm_pipe<<<nwg, 512, 0, stream>>>(feat, wt, x, flg, n_nodes);

  // --- out[node] = sum val * x[src] ---
  aggregate<<<(n_nodes + 3) / 4, 256, 0, stream>>>(x, esp, offs, counts, out, n_nodes);
}